// Round 2
// baseline (24146.727 us; speedup 1.0000x reference)
//
#include <hip/hip_runtime.h>
#include <hip/hip_bf16.h>

// Sizes (fixed by the problem)
#define BATCH 128
#define SEQ   512
#define IND   512
#define FSD   128
#define HS    512
#define G4    (4 * HS)   // 2048
#define G2    (2 * HS)   // 1024

// rec2 partitioning
#define NG 8    // batch groups
#define GB 16   // batches per group
#define NS 32   // hidden slices
#define SJ 16   // hidden per slice

typedef short short8_t __attribute__((ext_vector_type(8)));
typedef float f32x4 __attribute__((ext_vector_type(4)));

static __device__ __forceinline__ unsigned short f2bf(float f) {
    unsigned int u = __float_as_uint(f);
    unsigned int r = (u + 0x7fffu + ((u >> 16) & 1u)) >> 16;
    return (unsigned short)r;
}
static __device__ __forceinline__ float bf2f(unsigned short b) {
    return __uint_as_float(((unsigned int)b) << 16);
}
static __device__ __forceinline__ float sigmoidf_(float x) {
    return 1.0f / (1.0f + __expf(-x));
}

// ---------------------------------------------------------------------------
// Kernel 1: permute U_f [512][2048] f32 -> Up bf16 in MFMA B-fragment order.
// Up[(((s*4+g)*16+kt)*64+l)*8+i] = U_f[kt*32+(l>>4)*8+i][g*512+s*16+(l&15)]
// (lane l holds col=l&15, k=kt*32+(l>>4)*8+i for tile (s,g), 16 k-tiles)
// ---------------------------------------------------------------------------
__global__ __launch_bounds__(256)
void uconv_kernel(const float* __restrict__ Uf, unsigned short* __restrict__ Up) {
    int idx = blockIdx.x * 256 + threadIdx.x;   // 0 .. 2^20-1
    int i  = idx & 7;
    int l  = (idx >> 3) & 63;
    int kt = (idx >> 9) & 15;
    int g  = (idx >> 13) & 3;
    int s  = idx >> 15;
    int k  = kt * 32 + ((l >> 4) << 3) + i;
    int col = g * 512 + s * 16 + (l & 15);
    Up[idx] = f2bf(Uf[(size_t)k * G4 + col]);
}

// ---------------------------------------------------------------------------
// Kernel 2: lz = sigmoid(field@Wz[:, :512]+bz) * tanh(field@Wz[:, 512:]+bz)
// Output layout: lz[s][b][j] bf16
// ---------------------------------------------------------------------------
__global__ __launch_bounds__(256)
void lz_kernel(const float* __restrict__ field, const float* __restrict__ Wz,
               const float* __restrict__ biasz, unsigned short* __restrict__ lzOut) {
    __shared__ float fs[8][FSD];
    int b = blockIdx.x, s0 = blockIdx.y * 8;
    int tid = threadIdx.x;
    for (int u = tid; u < 8 * FSD; u += 256) {
        int r = u >> 7, k = u & 127;
        fs[r][k] = field[((size_t)b * SEQ + s0 + r) * FSD + k];
    }
    __syncthreads();
    #pragma unroll
    for (int jj = 0; jj < 2; ++jj) {
        int j = tid + jj * 256;
        float accl[8] = {0,0,0,0,0,0,0,0}, accz[8] = {0,0,0,0,0,0,0,0};
        for (int k = 0; k < FSD; ++k) {
            float wl = Wz[(size_t)k * G2 + j];
            float wz = Wz[(size_t)k * G2 + HS + j];
            #pragma unroll
            for (int r = 0; r < 8; ++r) {
                accl[r] += fs[r][k] * wl;
                accz[r] += fs[r][k] * wz;
            }
        }
        float bl = biasz[j], bz = biasz[HS + j];
        #pragma unroll
        for (int r = 0; r < 8; ++r) {
            float l = sigmoidf_(accl[r] + bl);
            float z = tanhf(accz[r] + bz);
            lzOut[(((size_t)(s0 + r)) * BATCH + b) * HS + j] = f2bf(l * z);
        }
    }
}

// ---------------------------------------------------------------------------
// Kernel 3: x_proj GEMM (f32 VALU tile GEMM), out bf16 [s][b][4H]
// ---------------------------------------------------------------------------
#define BM 64
#define BN 128
#define TK 32
__global__ __launch_bounds__(256)
void xproj_kernel(const float* __restrict__ word, const float* __restrict__ Wf,
                  const float* __restrict__ bias, unsigned short* __restrict__ xp) {
    __shared__ float As[TK][BM];
    __shared__ float Bs[TK][BN];
    int tid = threadIdx.x;
    int row0 = blockIdx.x * BM;
    int col0 = blockIdx.y * BN;
    int tx = tid & 15;
    int ty = tid >> 4;
    float acc[4][8];
    #pragma unroll
    for (int i = 0; i < 4; ++i)
        #pragma unroll
        for (int c = 0; c < 8; ++c) acc[i][c] = 0.f;

    int arow = tid & 63;
    int ak0 = (tid >> 6) * 8;
    int grow = row0 + arow;
    int b_ = grow & 127, s_ = grow >> 7;
    const float* aptr = word + ((size_t)b_ * SEQ + s_) * IND;
    int bk = tid >> 3;
    int bc0 = (tid & 7) * 16;

    for (int k0 = 0; k0 < IND; k0 += TK) {
        #pragma unroll
        for (int u = 0; u < 8; u += 4) {
            float4 v = *(const float4*)(aptr + k0 + ak0 + u);
            As[ak0 + u + 0][arow] = v.x;
            As[ak0 + u + 1][arow] = v.y;
            As[ak0 + u + 2][arow] = v.z;
            As[ak0 + u + 3][arow] = v.w;
        }
        #pragma unroll
        for (int u = 0; u < 16; u += 4) {
            float4 v = *(const float4*)(Wf + (size_t)(k0 + bk) * G4 + col0 + bc0 + u);
            *(float4*)&Bs[bk][bc0 + u] = v;
        }
        __syncthreads();
        #pragma unroll
        for (int kk = 0; kk < TK; ++kk) {
            float a0 = As[kk][ty], a1 = As[kk][ty + 16];
            float a2 = As[kk][ty + 32], a3 = As[kk][ty + 48];
            float bb[8];
            #pragma unroll
            for (int c = 0; c < 8; ++c) bb[c] = Bs[kk][tx * 8 + c];
            #pragma unroll
            for (int c = 0; c < 8; ++c) {
                acc[0][c] += a0 * bb[c];
                acc[1][c] += a1 * bb[c];
                acc[2][c] += a2 * bb[c];
                acc[3][c] += a3 * bb[c];
            }
        }
        __syncthreads();
    }
    #pragma unroll
    for (int rm = 0; rm < 4; ++rm) {
        int gr = row0 + ty + rm * 16;
        #pragma unroll
        for (int c = 0; c < 8; ++c) {
            int gc = col0 + tx * 8 + c;
            xp[(size_t)gr * G4 + gc] = f2bf(acc[rm][c] + bias[gc]);
        }
    }
}

// ---------------------------------------------------------------------------
// Kernel 4: recurrence, MFMA + multi-block per-step sync.
// Grid 256 blocks x 256 threads. Block bid: g=bid&7 (batch group, = XCD),
// s=bid>>3 (hidden slice). Waves = the 4 gates. U preloaded in registers.
// h exchanged via double-buffered global hbuf in A-fragment order.
// ---------------------------------------------------------------------------
__global__ __launch_bounds__(256)
void rec2_kernel(const unsigned short* __restrict__ xp,
                 const unsigned short* __restrict__ lz,
                 const unsigned short* __restrict__ Up,
                 float* __restrict__ out,
                 unsigned short* __restrict__ hbuf,
                 unsigned int* __restrict__ cnt) {
    const size_t HSEQ = (size_t)BATCH * SEQ * HS;   // 33,554,432
    const int HBG = GB * HS;                        // 8192 ushorts per group buf

    int bid = blockIdx.x;
    int g = bid & 7;
    int s = bid >> 3;
    int tid = threadIdx.x;
    int w = tid >> 6;     // wave index = gate (0:i 1:f 2:g 3:o)
    int l = tid & 63;

    // --- B preload: 16 k-tile fragments of U for (slice s, gate w) ---
    short8_t Bf[16];
    const short8_t* upw = (const short8_t*)(Up + ((size_t)(s * 4 + w) * 16) * 512);
    #pragma unroll
    for (int kt = 0; kt < 16; ++kt) Bf[kt] = upw[kt * 64 + l];

    __shared__ float gbuf[4][16][16];

    // epilogue ownership: one thread per (batch-local, j-local)
    int eb = tid >> 4;
    int ej = tid & 15;
    int jg = s * SJ + ej;        // global hidden index
    int bg = g * GB + eb;        // global batch index

    // hbuf write index (A-fragment order): value h[b][j] at
    // ((kt*64 + (b + 16*((j>>3)&3)))*8 + (j&7)), kt = j>>5
    int widx = (((jg >> 5) * 64 + eb + (((jg >> 3) & 3) << 4)) << 3) + (jg & 7);

    unsigned int* cg = cnt + g * SEQ;

    float c = 0.f;
    float h_last = 0.f;

    for (int t = 0; t < SEQ; ++t) {
        f32x4 acc0 = {0.f, 0.f, 0.f, 0.f};
        f32x4 acc1 = {0.f, 0.f, 0.f, 0.f};
        if (t > 0) {
            if (tid == 0) {
                int spins = 0;
                while (__hip_atomic_load(&cg[t - 1], __ATOMIC_ACQUIRE,
                                         __HIP_MEMORY_SCOPE_AGENT) < (unsigned)NS) {
                    if (++spins > (1 << 24)) break;   // hang guard
                }
            }
            __syncthreads();
            __threadfence();   // acquire: fresh view of hbuf for all threads

            const short8_t* ha =
                (const short8_t*)(hbuf + (size_t)((((t - 1) & 1) * NG) + g) * HBG);
            #pragma unroll
            for (int kt = 0; kt < 16; kt += 2) {
                short8_t a0 = ha[kt * 64 + l];
                short8_t a1 = ha[(kt + 1) * 64 + l];
                acc0 = __builtin_amdgcn_mfma_f32_16x16x32_bf16(a0, Bf[kt],     acc0, 0, 0, 0);
                acc1 = __builtin_amdgcn_mfma_f32_16x16x32_bf16(a1, Bf[kt + 1], acc1, 0, 0, 0);
            }
            acc0 += acc1;
        }
        // stash gate tile: D layout col=lane&15, row=(lane>>4)*4+reg
        #pragma unroll
        for (int r = 0; r < 4; ++r)
            gbuf[w][(l >> 4) * 4 + r][l & 15] = acc0[r];
        __syncthreads();

        // epilogue: thread (eb, ej)
        size_t xb = ((size_t)t * BATCH + bg) * G4;
        float gi = gbuf[0][eb][ej] + bf2f(xp[xb + jg]);
        float gf = gbuf[1][eb][ej] + bf2f(xp[xb + HS + jg]);
        float gg = gbuf[2][eb][ej] + bf2f(xp[xb + 2 * HS + jg]);
        float go = gbuf[3][eb][ej] + bf2f(xp[xb + 3 * HS + jg]);
        float i_ = sigmoidf_(gi);
        float f_ = sigmoidf_(gf + 1.0f);
        float g_ = tanhf(gg);
        float o_ = sigmoidf_(go);
        c = f_ * c + i_ * g_ + bf2f(lz[((size_t)t * BATCH + bg) * HS + jg]);
        float h = o_ * tanhf(c);
        h_last = h;
        out[((size_t)bg * SEQ + t) * HS + jg] = h;
        hbuf[(size_t)(((t & 1) * NG) + g) * HBG + widx] = f2bf(h);

        __threadfence();     // release: flush h before arrive
        __syncthreads();     // all threads' h written+fenced; gbuf reads done
        if (tid == 0)
            __hip_atomic_fetch_add(&cg[t], 1u, __ATOMIC_RELEASE,
                                   __HIP_MEMORY_SCOPE_AGENT);
    }

    // finals: h_T then c_T
    out[HSEQ + (size_t)bg * HS + jg] = h_last;
    out[HSEQ + (size_t)BATCH * HS + (size_t)bg * HS + jg] = c;
}

// ---------------------------------------------------------------------------
extern "C" void kernel_launch(void* const* d_in, const int* in_sizes, int n_in,
                              void* d_out, int out_size, void* d_ws, size_t ws_size,
                              hipStream_t stream) {
    const float* word   = (const float*)d_in[0];
    const float* field  = (const float*)d_in[1];
    const float* Wf     = (const float*)d_in[2];
    const float* Wz     = (const float*)d_in[3];
    const float* Uf     = (const float*)d_in[4];
    const float* bias_f = (const float*)d_in[5];
    const float* biasz  = (const float*)d_in[6];
    float* out = (float*)d_out;

    // Workspace layout (bytes):
    //   xp  : bf16 [S][B][4H] = 268,435,456
    //   lz  : bf16 [S][B][H]  =  67,108,864
    //   Up  : bf16 frag-order =   2,097,152
    //   hbuf: bf16 2x8x8192   =     262,144
    //   cnt : u32 8x512       =      16,384
    char* p = (char*)d_ws;
    unsigned short* xp  = (unsigned short*)p;  p += (size_t)SEQ * BATCH * G4 * 2;
    unsigned short* lzb = (unsigned short*)p;  p += (size_t)SEQ * BATCH * HS * 2;
    unsigned short* Up  = (unsigned short*)p;  p += (size_t)IND * G4 * 2;
    unsigned short* hbuf= (unsigned short*)p;  p += (size_t)2 * NG * GB * HS * 2;
    unsigned int*   cnt = (unsigned int*)p;    p += (size_t)NG * SEQ * 4;

    uconv_kernel<<<(IND * G4) / 256, 256, 0, stream>>>(Uf, Up);

    dim3 gl(BATCH, SEQ / 8);
    lz_kernel<<<gl, 256, 0, stream>>>(field, Wz, biasz, lzb);

    dim3 gx((SEQ * BATCH) / BM, G4 / BN);
    xproj_kernel<<<gx, 256, 0, stream>>>(word, Wf, bias_f, xp);

    hipMemsetAsync(cnt, 0, (size_t)NG * SEQ * 4, stream);

    rec2_kernel<<<NG * NS, 256, 0, stream>>>(xp, lzb, Up, out, hbuf, cnt);
}

// Round 3
// 2441.598 us; speedup vs baseline: 9.8897x; 9.8897x over previous
//
#include <hip/hip_runtime.h>
#include <hip/hip_bf16.h>

// Sizes (fixed by the problem)
#define BATCH 128
#define SEQ   512
#define IND   512
#define FSD   128
#define HS    512
#define G4    (4 * HS)   // 2048
#define G2    (2 * HS)   // 1024

// rec partitioning
#define NG 8    // batch groups
#define GB 16   // batches per group
#define NS 32   // hidden slices
#define SJ 16   // hidden per slice

typedef short short8_t __attribute__((ext_vector_type(8)));
typedef float f32x4 __attribute__((ext_vector_type(4)));

static __device__ __forceinline__ unsigned short f2bf(float f) {
    unsigned int u = __float_as_uint(f);
    unsigned int r = (u + 0x7fffu + ((u >> 16) & 1u)) >> 16;
    return (unsigned short)r;
}
static __device__ __forceinline__ float bf2f(unsigned short b) {
    return __uint_as_float(((unsigned int)b) << 16);
}
static __device__ __forceinline__ float sigmoidf_(float x) {
    return 1.0f / (1.0f + __expf(-x));
}

// ---------------------------------------------------------------------------
// Kernel 1: permute U_f [512][2048] f32 -> Up bf16 in MFMA B-fragment order.
// Up[(((s*4+g)*16+kt)*64+l)*8+i] = U_f[kt*32+(l>>4)*8+i][g*512+s*16+(l&15)]
// ---------------------------------------------------------------------------
__global__ __launch_bounds__(256)
void uconv_kernel(const float* __restrict__ Uf, unsigned short* __restrict__ Up) {
    int idx = blockIdx.x * 256 + threadIdx.x;   // 0 .. 2^20-1
    int i  = idx & 7;
    int l  = (idx >> 3) & 63;
    int kt = (idx >> 9) & 15;
    int g  = (idx >> 13) & 3;
    int s  = idx >> 15;
    int k  = kt * 32 + ((l >> 4) << 3) + i;
    int col = g * 512 + s * 16 + (l & 15);
    Up[idx] = f2bf(Uf[(size_t)k * G4 + col]);
}

// ---------------------------------------------------------------------------
// Kernel 1b: transpose+convert W_f [512][2048] f32 -> WfT [2048][512] bf16
// ---------------------------------------------------------------------------
__global__ __launch_bounds__(256)
void wtconv_kernel(const float* __restrict__ Wf, unsigned short* __restrict__ WfT) {
    __shared__ float tile[64][65];
    int k0 = blockIdx.x * 64;
    int n0 = blockIdx.y * 64;
    int tid = threadIdx.x;
    int r = tid >> 6, c = tid & 63;
    #pragma unroll
    for (int i = 0; i < 16; ++i)
        tile[r + 4 * i][c] = Wf[(size_t)(k0 + r + 4 * i) * G4 + n0 + c];
    __syncthreads();
    #pragma unroll
    for (int i = 0; i < 16; ++i)
        WfT[(size_t)(n0 + r + 4 * i) * IND + k0 + c] = f2bf(tile[c][r + 4 * i]);
}

// ---------------------------------------------------------------------------
// Kernel 2: lz = sigmoid(field@Wz[:, :512]+bz) * tanh(field@Wz[:, 512:]+bz)
// Output layout: lz[s][b][j] bf16
// ---------------------------------------------------------------------------
__global__ __launch_bounds__(256)
void lz_kernel(const float* __restrict__ field, const float* __restrict__ Wz,
               const float* __restrict__ biasz, unsigned short* __restrict__ lzOut) {
    __shared__ float fs[8][FSD];
    int b = blockIdx.x, s0 = blockIdx.y * 8;
    int tid = threadIdx.x;
    for (int u = tid; u < 8 * FSD; u += 256) {
        int r = u >> 7, k = u & 127;
        fs[r][k] = field[((size_t)b * SEQ + s0 + r) * FSD + k];
    }
    __syncthreads();
    #pragma unroll
    for (int jj = 0; jj < 2; ++jj) {
        int j = tid + jj * 256;
        float accl[8] = {0,0,0,0,0,0,0,0}, accz[8] = {0,0,0,0,0,0,0,0};
        for (int k = 0; k < FSD; ++k) {
            float wl = Wz[(size_t)k * G2 + j];
            float wz = Wz[(size_t)k * G2 + HS + j];
            #pragma unroll
            for (int r = 0; r < 8; ++r) {
                accl[r] += fs[r][k] * wl;
                accz[r] += fs[r][k] * wz;
            }
        }
        float bl = biasz[j], bz = biasz[HS + j];
        #pragma unroll
        for (int r = 0; r < 8; ++r) {
            float l = sigmoidf_(accl[r] + bl);
            float z = tanhf(accz[r] + bz);
            lzOut[(((size_t)(s0 + r)) * BATCH + b) * HS + j] = f2bf(l * z);
        }
    }
}

// ---------------------------------------------------------------------------
// Kernel 3: x_proj MFMA GEMM. A = word (f32, converted on the fly) with
// row = s*128+b; B = WfT bf16 [n][k]. C -> xp bf16 [s][b][4H] (+bias).
// Tile 128x128, BK=64, 4 waves (2x2 of 64x64), XOR-swizzled LDS.
// ---------------------------------------------------------------------------
#define XBM 128
#define XBN 128
#define XBK 64
__global__ __launch_bounds__(256)
void xmm_kernel(const float* __restrict__ word, const unsigned short* __restrict__ WfT,
                const float* __restrict__ bias, unsigned short* __restrict__ xp) {
    __shared__ unsigned short As[XBM * XBK];
    __shared__ unsigned short Bs[XBN * XBK];
    int tid = threadIdx.x;
    int l = tid & 63, w = tid >> 6;
    int wr = w >> 1, wc = w & 1;
    int row0 = blockIdx.x * XBM;
    int col0 = blockIdx.y * XBN;

    f32x4 acc[4][4];
    #pragma unroll
    for (int m = 0; m < 4; ++m)
        #pragma unroll
        for (int n = 0; n < 4; ++n)
            acc[m][n] = (f32x4){0.f, 0.f, 0.f, 0.f};

    for (int k0 = 0; k0 < IND; k0 += XBK) {
        float4 av[4][2];
        short8_t bv[4];
        #pragma unroll
        for (int i = 0; i < 4; ++i) {
            int c = tid + 256 * i;
            int ar = c >> 3, sub = c & 7;
            int grow = row0 + ar;
            int b_ = grow & 127, s_ = grow >> 7;
            const float* ap = word + ((size_t)b_ * SEQ + s_) * IND + k0 + sub * 8;
            av[i][0] = *(const float4*)ap;
            av[i][1] = *(const float4*)(ap + 4);
            bv[i] = *(const short8_t*)(WfT + (size_t)(col0 + ar) * IND + k0 + sub * 8);
        }
        __syncthreads();   // previous iter's compute done with LDS
        #pragma unroll
        for (int i = 0; i < 4; ++i) {
            int c = tid + 256 * i;
            int ar = c >> 3, sub = c & 7;
            int off = ar * 64 + ((sub ^ (ar & 7)) << 3);   // ushort units
            short8_t a8;
            a8[0] = (short)f2bf(av[i][0].x); a8[1] = (short)f2bf(av[i][0].y);
            a8[2] = (short)f2bf(av[i][0].z); a8[3] = (short)f2bf(av[i][0].w);
            a8[4] = (short)f2bf(av[i][1].x); a8[5] = (short)f2bf(av[i][1].y);
            a8[6] = (short)f2bf(av[i][1].z); a8[7] = (short)f2bf(av[i][1].w);
            *(short8_t*)&As[off] = a8;
            *(short8_t*)&Bs[off] = bv[i];
        }
        __syncthreads();
        #pragma unroll
        for (int kt = 0; kt < 2; ++kt) {
            short8_t af[4], bfr[4];
            #pragma unroll
            for (int m = 0; m < 4; ++m) {
                int r = wr * 64 + m * 16 + (l & 15);
                int sub = kt * 4 + (l >> 4);
                af[m] = *(const short8_t*)&As[r * 64 + ((sub ^ (r & 7)) << 3)];
                int cc = wc * 64 + m * 16 + (l & 15);
                bfr[m] = *(const short8_t*)&Bs[cc * 64 + ((sub ^ (cc & 7)) << 3)];
            }
            #pragma unroll
            for (int m = 0; m < 4; ++m)
                #pragma unroll
                for (int n = 0; n < 4; ++n)
                    acc[m][n] = __builtin_amdgcn_mfma_f32_16x16x32_bf16(
                        af[m], bfr[n], acc[m][n], 0, 0, 0);
        }
    }
    #pragma unroll
    for (int m = 0; m < 4; ++m) {
        int grow = row0 + wr * 64 + m * 16 + (l >> 4) * 4;
        #pragma unroll
        for (int n = 0; n < 4; ++n) {
            int gcol = col0 + wc * 64 + n * 16 + (l & 15);
            float bsv = bias[gcol];
            #pragma unroll
            for (int r = 0; r < 4; ++r)
                xp[(size_t)(grow + r) * G4 + gcol] = f2bf(acc[m][n][r] + bsv);
        }
    }
}

// ---------------------------------------------------------------------------
// Kernel 4: recurrence. Same MFMA structure as round 2 (verified), but sync
// via RELAXED agent atomics only (sc-bit cache-bypass ops, NO fences),
// ordering by s_waitcnt vmcnt(0). xp/lz prefetched before the spin.
// ---------------------------------------------------------------------------
__global__ __launch_bounds__(256)
void rec3_kernel(const unsigned short* __restrict__ xp,
                 const unsigned short* __restrict__ lz,
                 const unsigned short* __restrict__ Up,
                 float* __restrict__ out,
                 unsigned short* __restrict__ hbuf,
                 unsigned int* __restrict__ cnt) {
    const size_t HSEQ = (size_t)BATCH * SEQ * HS;
    const int HBG = GB * HS;                        // 8192 ushorts per group buf

    int bid = blockIdx.x;
    int g = bid & 7;
    int s = bid >> 3;
    int tid = threadIdx.x;
    int w = tid >> 6;
    int l = tid & 63;

    // B preload: 16 k-tile fragments of U for (slice s, gate w)
    short8_t Bf[16];
    const short8_t* upw = (const short8_t*)(Up + ((size_t)(s * 4 + w) * 16) * 512);
    #pragma unroll
    for (int kt = 0; kt < 16; ++kt) Bf[kt] = upw[kt * 64 + l];

    __shared__ float gbuf[4][16][17];   // padded: no bank conflicts

    int eb = tid >> 4;
    int ej = tid & 15;
    int jg = s * SJ + ej;
    int bg = g * GB + eb;

    // hbuf A-fragment index for value h[b][j]
    int widx = (((jg >> 5) * 64 + eb + (((jg >> 3) & 3) << 4)) << 3) + (jg & 7);

    unsigned int* cg = cnt + g * SEQ;

    float c = 0.f;
    float h_last = 0.f;

    for (int t = 0; t < SEQ; ++t) {
        // prefetch gate inputs (independent of h) — overlap with the spin
        size_t xb = ((size_t)t * BATCH + bg) * G4;
        float pgi = bf2f(xp[xb + jg]);
        float pgf = bf2f(xp[xb + HS + jg]);
        float pgg = bf2f(xp[xb + 2 * HS + jg]);
        float pgo = bf2f(xp[xb + 3 * HS + jg]);
        float plz = bf2f(lz[((size_t)t * BATCH + bg) * HS + jg]);

        f32x4 acc0 = {0.f, 0.f, 0.f, 0.f};
        f32x4 acc1 = {0.f, 0.f, 0.f, 0.f};
        if (t > 0) {
            if (tid == 0) {
                int spins = 0;
                while (__hip_atomic_load(&cg[t - 1], __ATOMIC_RELAXED,
                                         __HIP_MEMORY_SCOPE_AGENT) < (unsigned)NS) {
                    if (++spins > (1 << 18)) break;   // hang guard
                }
            }
            __syncthreads();

            const unsigned long long* ha64 = (const unsigned long long*)
                (hbuf + (size_t)((((t - 1) & 1) * NG) + g) * HBG);
            #pragma unroll
            for (int kt = 0; kt < 16; kt += 2) {
                union { unsigned long long u[2]; short8_t v; } A0, A1;
                int i0 = (kt * 64 + l) * 2;
                int i1 = ((kt + 1) * 64 + l) * 2;
                A0.u[0] = __hip_atomic_load(&ha64[i0], __ATOMIC_RELAXED,
                                            __HIP_MEMORY_SCOPE_AGENT);
                A0.u[1] = __hip_atomic_load(&ha64[i0 + 1], __ATOMIC_RELAXED,
                                            __HIP_MEMORY_SCOPE_AGENT);
                A1.u[0] = __hip_atomic_load(&ha64[i1], __ATOMIC_RELAXED,
                                            __HIP_MEMORY_SCOPE_AGENT);
                A1.u[1] = __hip_atomic_load(&ha64[i1 + 1], __ATOMIC_RELAXED,
                                            __HIP_MEMORY_SCOPE_AGENT);
                acc0 = __builtin_amdgcn_mfma_f32_16x16x32_bf16(A0.v, Bf[kt],     acc0, 0, 0, 0);
                acc1 = __builtin_amdgcn_mfma_f32_16x16x32_bf16(A1.v, Bf[kt + 1], acc1, 0, 0, 0);
            }
            acc0 += acc1;
        }
        #pragma unroll
        for (int r = 0; r < 4; ++r)
            gbuf[w][(l >> 4) * 4 + r][l & 15] = acc0[r];
        __syncthreads();

        // epilogue: thread (eb, ej)
        float gi = gbuf[0][eb][ej] + pgi;
        float gf = gbuf[1][eb][ej] + pgf;
        float gg = gbuf[2][eb][ej] + pgg;
        float go = gbuf[3][eb][ej] + pgo;
        float i_ = sigmoidf_(gi);
        float f_ = sigmoidf_(gf + 1.0f);
        float g_ = tanhf(gg);
        float o_ = sigmoidf_(go);
        c = f_ * c + i_ * g_ + plz;
        float h = o_ * tanhf(c);
        h_last = h;
        out[((size_t)bg * SEQ + t) * HS + jg] = h;

        // h exchange: pack pairs, relaxed agent atomic store (write-through)
        unsigned short hv = f2bf(h);
        unsigned int partner = (unsigned int)(unsigned short)__shfl_down((int)hv, 1);
        if ((ej & 1) == 0) {
            unsigned int* hb32 = (unsigned int*)
                (hbuf + (size_t)(((t & 1) * NG) + g) * HBG);
            __hip_atomic_store(&hb32[widx >> 1], (unsigned int)hv | (partner << 16),
                               __ATOMIC_RELAXED, __HIP_MEMORY_SCOPE_AGENT);
        }
        asm volatile("s_waitcnt vmcnt(0)" ::: "memory");
        __syncthreads();   // all threads' h stores completed at coherence point
        if (tid == 0)
            __hip_atomic_fetch_add(&cg[t], 1u, __ATOMIC_RELAXED,
                                   __HIP_MEMORY_SCOPE_AGENT);
    }

    out[HSEQ + (size_t)bg * HS + jg] = h_last;
    out[HSEQ + (size_t)BATCH * HS + (size_t)bg * HS + jg] = c;
}

// ---------------------------------------------------------------------------
extern "C" void kernel_launch(void* const* d_in, const int* in_sizes, int n_in,
                              void* d_out, int out_size, void* d_ws, size_t ws_size,
                              hipStream_t stream) {
    const float* word   = (const float*)d_in[0];
    const float* field  = (const float*)d_in[1];
    const float* Wf     = (const float*)d_in[2];
    const float* Wz     = (const float*)d_in[3];
    const float* Uf     = (const float*)d_in[4];
    const float* bias_f = (const float*)d_in[5];
    const float* biasz  = (const float*)d_in[6];
    float* out = (float*)d_out;

    // Workspace:
    //   xp  : bf16 [S][B][4H] = 268,435,456
    //   lz  : bf16 [S][B][H]  =  67,108,864
    //   Up  : bf16 frag-order =   2,097,152
    //   WfT : bf16 [N][K]     =   2,097,152
    //   hbuf: bf16 2x8x8192   =     262,144
    //   cnt : u32 8x512       =      16,384
    char* p = (char*)d_ws;
    unsigned short* xp  = (unsigned short*)p;  p += (size_t)SEQ * BATCH * G4 * 2;
    unsigned short* lzb = (unsigned short*)p;  p += (size_t)SEQ * BATCH * HS * 2;
    unsigned short* Up  = (unsigned short*)p;  p += (size_t)IND * G4 * 2;
    unsigned short* WfT = (unsigned short*)p;  p += (size_t)G4 * IND * 2;
    unsigned short* hbuf= (unsigned short*)p;  p += (size_t)2 * NG * GB * HS * 2;
    unsigned int*   cnt = (unsigned int*)p;    p += (size_t)NG * SEQ * 4;

    uconv_kernel<<<(IND * G4) / 256, 256, 0, stream>>>(Uf, Up);

    dim3 gt(IND / 64, G4 / 64);
    wtconv_kernel<<<gt, 256, 0, stream>>>(Wf, WfT);

    dim3 gl(BATCH, SEQ / 8);
    lz_kernel<<<gl, 256, 0, stream>>>(field, Wz, biasz, lzb);

    hipMemsetAsync(cnt, 0, (size_t)NG * SEQ * 4, stream);

    dim3 gx((SEQ * BATCH) / XBM, G4 / XBN);
    xmm_kernel<<<gx, 256, 0, stream>>>(word, WfT, bias_f, xp);

    rec3_kernel<<<NG * NS, 256, 0, stream>>>(xp, lzb, Up, out, hbuf, cnt);
}